// Round 12
// baseline (157.362 us; speedup 1.0000x reference)
//
#include <hip/hip_runtime.h>
#include <math.h>

#define B    256
#define NIN  1152
#define IND  8
#define NOUT 10
#define OUTD 16
#define M    160          // NOUT*OUTD
#define K    9216         // NIN*IND

typedef _Float16 h2    __attribute__((ext_vector_type(2)));
typedef _Float16 f16x4 __attribute__((ext_vector_type(4)));
typedef _Float16 f16x8 __attribute__((ext_vector_type(8)));
typedef float    f32x4 __attribute__((ext_vector_type(4)));
struct __align__(16) H8 { h2 h[4]; };   // 8 f16
struct __align__(8)  H4 { h2 h[2]; };   // 4 f16

// ================= prep: W f32 -> Wh f16 (same layout) =================
__global__ __launch_bounds__(256) void k_w16(const float* __restrict__ W,
                                             _Float16* __restrict__ Wh) {
    const int t = blockIdx.x * 256 + threadIdx.x;
    const float4 f = *(const float4*)(W + (size_t)t * 4);
    H4 p;
    p.h[0] = h2{(_Float16)f.x, (_Float16)f.y};
    p.h[1] = h2{(_Float16)f.z, (_Float16)f.w};
    *(H4*)(Wh + (size_t)t * 4) = p;
}

// ================= prep: u f32 -> u16 f16 (same layout) =================
__global__ __launch_bounds__(256) void k_u16(const float* __restrict__ u,
                                             _Float16* __restrict__ u16) {
    const size_t t = (size_t)blockIdx.x * 256 + threadIdx.x;   // x4 elems
    const float4 f = *(const float4*)(u + t * 4);
    H4 p;
    p.h[0] = h2{(_Float16)f.x, (_Float16)f.y};
    p.h[1] = h2{(_Float16)f.z, (_Float16)f.w};
    *(H4*)(u16 + t * 4) = p;
}

// ================= prep: W -> Wt f16 [n][o][d][i] (k_su B-fragment layout) =========
__global__ __launch_bounds__(256) void k_wt(const float* __restrict__ W,
                                            _Float16* __restrict__ Wt) {
    __shared__ float wl[IND * M];   // 5120 B
    const int n = blockIdx.x;
    const float* src = W + (size_t)n * IND * M;
    for (int t = threadIdx.x; t < IND * M / 4; t += 256)
        *(float4*)(wl + t * 4) = *(const float4*)(src + (size_t)t * 4);
    __syncthreads();
    const int t = threadIdx.x;
    if (t < 160) {
        const int o = t >> 4, d = t & 15;
        f16x8 out;
#pragma unroll
        for (int i = 0; i < IND; ++i) out[i] = (_Float16)wl[i * M + o * OUTD + d];
        *(f16x8*)(Wt + (((size_t)n * NOUT + o) * OUTD + d) * IND) = out;
    }
}

// ================= k_su: MFMA 16x16x32 f16 (round-11 form, verified) =================
#define NSPLIT 96
#define GPS    3      // n-groups (of 4 n) per split: 96*3*4 = 1152

template <int MODE>   // 0: c = 0.1 uniform; 1: read cbuf (f16)
__global__ __launch_bounds__(128, 4) void k_su(const _Float16* __restrict__ u16,
                                               const _Float16* __restrict__ Wt,
                                               const _Float16* __restrict__ cbuf,
                                               _Float16* __restrict__ spart) {
    const int lane  = threadIdx.x & 63;
    const int wv    = threadIdx.x >> 6;     // 0..1
    const int btile = blockIdx.x;           // 0..15
    const int split = blockIdx.y;           // 0..95
    const int bl    = lane & 15;            // A-row / b-local, B-col / d
    const int q     = lane >> 4;            // k-block = n offset within group
    const int b     = btile * 16 + bl;
    const int nbase = split * (GPS * 4);

    f32x4 acc[5];
#pragma unroll
    for (int j = 0; j < 5; ++j) acc[j] = f32x4{0.f, 0.f, 0.f, 0.f};

#pragma unroll
    for (int g = 0; g < GPS; ++g) {
        const int n = nbase + g * 4 + q;
        const f16x8 uf = *(const f16x8*)(u16 + ((size_t)b * NIN + n) * IND);
#pragma unroll
        for (int j = 0; j < 5; ++j) {
            const int o = wv * 5 + j;
            f16x8 a;
            if (MODE) {
                const _Float16 cv = cbuf[((size_t)o * NIN + n) * B + b];
#pragma unroll
                for (int i = 0; i < IND; ++i) a[i] = uf[i] * cv;
            } else {
                a = uf;
            }
            const f16x8 bf =
                *(const f16x8*)(Wt + (((size_t)n * NOUT + o) * OUTD + bl) * IND);
            acc[j] = __builtin_amdgcn_mfma_f32_16x16x32_f16(a, bf, acc[j], 0, 0, 0);
        }
    }

    const float scale = MODE ? 1.0f : 0.1f;
    _Float16* sp = spart + (size_t)split * B * M + ((size_t)btile * 16) * M;
#pragma unroll
    for (int r = 0; r < 4; ++r) {
        const int brow = q * 4 + r;
#pragma unroll
        for (int j = 0; j < 5; ++j) {
            const int o = wv * 5 + j;
            sp[(size_t)brow * M + o * OUTD + bl] = (_Float16)(acc[j][r] * scale);
        }
    }
}

// ================= k_squash: reduce NSPLIT f16 partials + squash ==================
template <int OUT16>
__global__ __launch_bounds__(64) void k_squash(const _Float16* __restrict__ spart,
                                               void* __restrict__ dstv) {
    const int gid = blockIdx.x * 64 + threadIdx.x;   // 0..40959, = b*160+m
    float s = 0.f;
#pragma unroll 16
    for (int ch = 0; ch < NSPLIT; ++ch) s += (float)spart[(size_t)ch * B * M + gid];
    float ss = s * s;
    ss += __shfl_xor(ss, 1);
    ss += __shfl_xor(ss, 2);
    ss += __shfl_xor(ss, 4);
    ss += __shfl_xor(ss, 8);          // sum over the 16 d-lanes (160 % 16 == 0)
    const float v = s * sqrtf(ss) / (1.f + ss);
    if (OUT16) ((_Float16*)dstv)[gid] = (_Float16)v;
    else       ((float*)dstv)[gid]    = v;
}

// ================= k_a (MFMA): a[b,n,o] = sum_i u * C[b,(n,i)] ==================
// C[b,(n,i)] = sum_d v[b,od]*W[n,i,od] via mfma 16x16x16 f16:
//   A = v-tile (row=b=lane&15, k=d=(lane>>4)*4+j)  -> v16[b][o*16+d], 8B/lane
//   B = W-tile (col=(n_loc,i)=lane&15, k=d)        -> Wh[(n*8+i)*160+o*16+d], 8B/lane
//   C: col=lane&15=(n_loc,i), row=(lane>>4)*4+reg=b-local   [same mapping k_su verified]
// Then val=C*u, sum over i = shfl_xor 1/2/4; masked (i==0) softmax; packed 8B writes.
#define NPW  4     // n-pairs per block (one per wave)
#define NBT  2     // 16-row b-tiles per wave

template <int FIRST>
__global__ __launch_bounds__(256, 8) void k_a(const _Float16* __restrict__ u16,
                                              const _Float16* __restrict__ Wh,
                                              const _Float16* __restrict__ v16,
                                              _Float16* __restrict__ blog,
                                              _Float16* __restrict__ cbuf) {
    const int lane = threadIdx.x & 63;
    const int wv   = threadIdx.x >> 6;          // 0..3
    const int np   = blockIdx.x * NPW + wv;     // 0..575 n-pair
    const int col  = lane & 15;                 // (n_loc, i)
    const int q    = lane >> 4;
    const int nl   = col >> 3;                  // n within pair
    const int ii   = col & 7;                   // i
    const int n    = np * 2 + nl;

    // B-fragments: one per o, reused across b-tiles
    f16x4 bf[NOUT];
    {
        const _Float16* wb = Wh + ((size_t)n * IND + ii) * M + q * 4;
#pragma unroll
        for (int o = 0; o < NOUT; ++o) bf[o] = *(const f16x4*)(wb + o * OUTD);
    }

    const f32x4 zero = {0.f, 0.f, 0.f, 0.f};

#pragma unroll
    for (int bt = 0; bt < NBT; ++bt) {
        const int b0 = blockIdx.y * (16 * NBT) + bt * 16;

        // u gathers: ur[r] = u16[b0+q*4+r][n][ii]
        float ur[4];
#pragma unroll
        for (int r = 0; r < 4; ++r)
            ur[r] = (float)u16[((size_t)(b0 + q * 4 + r) * NIN + n) * IND + ii];

        float areg[NOUT][4];
#pragma unroll
        for (int o = 0; o < NOUT; ++o) {
            const f16x4 av = *(const f16x4*)(v16 + (size_t)(b0 + col) * M + o * OUTD + q * 4);
            f32x4 c = __builtin_amdgcn_mfma_f32_16x16x16f16(av, bf[o], zero, 0, 0, 0);
#pragma unroll
            for (int r = 0; r < 4; ++r) {
                float val = c[r] * ur[r];
                val += __shfl_xor(val, 1);
                val += __shfl_xor(val, 2);
                val += __shfl_xor(val, 4);     // sum over i
                areg[o][r] = val;
            }
        }

        // masked softmax: lanes with ii==0 own (4 b-rows x 1 n x 10 o)
        if (ii == 0) {
            const int bq = b0 + q * 4;
            _Float16* bp = blog + ((size_t)n * NOUT) * B + bq;
            float bl[NOUT][4];
            if (FIRST) {
#pragma unroll
                for (int o = 0; o < NOUT; ++o) {
                    H4 pk;
#pragma unroll
                    for (int r = 0; r < 4; ++r) bl[o][r] = areg[o][r];
                    pk.h[0] = h2{(_Float16)bl[o][0], (_Float16)bl[o][1]};
                    pk.h[1] = h2{(_Float16)bl[o][2], (_Float16)bl[o][3]};
                    *(H4*)(bp + (size_t)o * B) = pk;
                }
            } else {
#pragma unroll
                for (int o = 0; o < NOUT; ++o) {
                    const H4 pk = *(const H4*)(bp + (size_t)o * B);
                    bl[o][0] = (float)pk.h[0][0] + areg[o][0];
                    bl[o][1] = (float)pk.h[0][1] + areg[o][1];
                    bl[o][2] = (float)pk.h[1][0] + areg[o][2];
                    bl[o][3] = (float)pk.h[1][1] + areg[o][3];
                }
            }
#pragma unroll
            for (int r = 0; r < 4; ++r) {
                float mx = bl[0][r];
#pragma unroll
                for (int o = 1; o < NOUT; ++o) mx = fmaxf(mx, bl[o][r]);
                float sum = 0.f;
#pragma unroll
                for (int o = 0; o < NOUT; ++o) { bl[o][r] = __expf(bl[o][r] - mx); sum += bl[o][r]; }
                const float inv = 1.f / sum;
#pragma unroll
                for (int o = 0; o < NOUT; ++o) bl[o][r] *= inv;
            }
#pragma unroll
            for (int o = 0; o < NOUT; ++o) {
                H4 pk;
                pk.h[0] = h2{(_Float16)bl[o][0], (_Float16)bl[o][1]};
                pk.h[1] = h2{(_Float16)bl[o][2], (_Float16)bl[o][3]};
                *(H4*)(cbuf + ((size_t)o * NIN + n) * B + bq) = pk;
            }
        }
    }
}

// ================= launch ==================
extern "C" void kernel_launch(void* const* d_in, const int* in_sizes, int n_in,
                              void* d_out, int out_size, void* d_ws, size_t ws_size,
                              hipStream_t stream) {
    const float* u = (const float*)d_in[0];   // [256,1152,8]
    const float* W = (const float*)d_in[1];   // [1152,8,160]
    float* out = (float*)d_out;               // [256,10,16] f32

    char* ws = (char*)d_ws;
    _Float16* spart = (_Float16*)(ws);                      //  7,864,320 B
    _Float16* blog  = (_Float16*)(ws + 7864320);            //  5,898,240 B
    _Float16* cbuf  = (_Float16*)(ws + 13762560);           //  5,898,240 B
    _Float16* v16   = (_Float16*)(ws + 19660800);           //     81,920 B
    _Float16* Wh    = (_Float16*)(ws + 19742720);           //  2,949,120 B
    _Float16* Wt    = (_Float16*)(ws + 22691840);           //  2,949,120 B
    _Float16* u16   = (_Float16*)(ws + 25640960);           //  4,718,592 B
    // total 30,359,552 B (~30.4 MB)

    const dim3 gs(16, NSPLIT);               // (16, 96) = 1536 blocks
    const dim3 ga(NIN / 2 / NPW, B / (16 * NBT));   // (144, 8) = 1152 blocks

    // one-time preps
    k_w16<<<1440, 256, 0, stream>>>(W, Wh);
    k_wt<<<NIN, 256, 0, stream>>>(W, Wt);
    k_u16<<<2304, 256, 0, stream>>>(u, u16);

    // iter 0: uniform c = 0.1
    k_su<0><<<gs, 128, 0, stream>>>(u16, Wt, cbuf, spart);
    k_squash<1><<<640, 64, 0, stream>>>(spart, v16);
    // a0 -> blog=b1, c1
    k_a<1><<<ga, 256, 0, stream>>>(u16, Wh, v16, blog, cbuf);
    // s1 -> v1
    k_su<1><<<gs, 128, 0, stream>>>(u16, Wt, cbuf, spart);
    k_squash<1><<<640, 64, 0, stream>>>(spart, v16);
    // a1 -> b2 (in-register), c2
    k_a<0><<<ga, 256, 0, stream>>>(u16, Wh, v16, blog, cbuf);
    // s2 -> v2 = output
    k_su<1><<<gs, 128, 0, stream>>>(u16, Wt, cbuf, spart);
    k_squash<0><<<640, 64, 0, stream>>>(spart, out);
}

// Round 13
// 89.771 us; speedup vs baseline: 1.7529x; 1.7529x over previous
//
#include <hip/hip_runtime.h>
#include <math.h>

#define B    256
#define NIN  1152
#define IND  8
#define NOUT 10
#define OUTD 16
#define M    160          // NOUT*OUTD
#define K    9216         // NIN*IND

typedef _Float16 h2    __attribute__((ext_vector_type(2)));
typedef _Float16 f16x4 __attribute__((ext_vector_type(4)));
typedef _Float16 f16x8 __attribute__((ext_vector_type(8)));
typedef float    f32x4 __attribute__((ext_vector_type(4)));
struct __align__(16) H8 { h2 h[4]; };   // 8 f16
struct __align__(8)  H4 { h2 h[2]; };   // 4 f16

// ================= prep: W f32 -> Wh f16 (same layout) =================
__global__ __launch_bounds__(256) void k_w16(const float* __restrict__ W,
                                             _Float16* __restrict__ Wh) {
    const int t = blockIdx.x * 256 + threadIdx.x;
    const float4 f = *(const float4*)(W + (size_t)t * 4);
    H4 p;
    p.h[0] = h2{(_Float16)f.x, (_Float16)f.y};
    p.h[1] = h2{(_Float16)f.z, (_Float16)f.w};
    *(H4*)(Wh + (size_t)t * 4) = p;
}

// ================= prep: u f32 -> u16 f16 (same layout, for k_su) =================
__global__ __launch_bounds__(256) void k_u16(const float* __restrict__ u,
                                             _Float16* __restrict__ u16) {
    const size_t t = (size_t)blockIdx.x * 256 + threadIdx.x;   // x4 elems
    const float4 f = *(const float4*)(u + t * 4);
    H4 p;
    p.h[0] = h2{(_Float16)f.x, (_Float16)f.y};
    p.h[1] = h2{(_Float16)f.z, (_Float16)f.w};
    *(H4*)(u16 + t * 4) = p;
}

// ================= prep: u f32 -> ut f16 [k=n*8+i][b] (transpose, for k_a) =========
__global__ __launch_bounds__(256) void k_ut(const float* __restrict__ u,
                                            _Float16* __restrict__ ut) {
    __shared__ _Float16 lt[64][80];   // pad 80 -> 160B row stride (16B-aligned)
    const int k0 = blockIdx.x * 64;   // 144
    const int b0 = blockIdx.y * 64;   // 4
#pragma unroll
    for (int p = 0; p < 4; ++p) {
        const int r = (threadIdx.x >> 4) + p * 16;   // b-local 0..63
        const int c = (threadIdx.x & 15) * 4;        // k-local
        const float4 f = *(const float4*)(u + (size_t)(b0 + r) * K + k0 + c);
        lt[c + 0][r] = (_Float16)f.x;
        lt[c + 1][r] = (_Float16)f.y;
        lt[c + 2][r] = (_Float16)f.z;
        lt[c + 3][r] = (_Float16)f.w;
    }
    __syncthreads();
#pragma unroll
    for (int p = 0; p < 2; ++p) {
        const int kr = (threadIdx.x >> 3) + p * 32;  // k-local 0..63
        const int bc = (threadIdx.x & 7) * 8;        // b-local
        *(uint4*)(ut + (size_t)(k0 + kr) * B + b0 + bc) = *(const uint4*)&lt[kr][bc];
    }
}

// ================= prep: W -> Wt f16 [n][o][d][i] (k_su B-fragment layout) =========
__global__ __launch_bounds__(256) void k_wt(const float* __restrict__ W,
                                            _Float16* __restrict__ Wt) {
    __shared__ float wl[IND * M];   // 5120 B
    const int n = blockIdx.x;
    const float* src = W + (size_t)n * IND * M;
    for (int t = threadIdx.x; t < IND * M / 4; t += 256)
        *(float4*)(wl + t * 4) = *(const float4*)(src + (size_t)t * 4);
    __syncthreads();
    const int t = threadIdx.x;
    if (t < 160) {
        const int o = t >> 4, d = t & 15;
        f16x8 out;
#pragma unroll
        for (int i = 0; i < IND; ++i) out[i] = (_Float16)wl[i * M + o * OUTD + d];
        *(f16x8*)(Wt + (((size_t)n * NOUT + o) * OUTD + d) * IND) = out;
    }
}

// ================= k_su: MFMA 16x16x32 f16 (round-11 form, verified) =================
#define NSPLIT 96
#define GPS    3      // n-groups (of 4 n) per split: 96*3*4 = 1152

template <int MODE>   // 0: c = 0.1 uniform; 1: read cbuf (f16)
__global__ __launch_bounds__(128, 4) void k_su(const _Float16* __restrict__ u16,
                                               const _Float16* __restrict__ Wt,
                                               const _Float16* __restrict__ cbuf,
                                               _Float16* __restrict__ spart) {
    const int lane  = threadIdx.x & 63;
    const int wv    = threadIdx.x >> 6;     // 0..1
    const int btile = blockIdx.x;           // 0..15
    const int split = blockIdx.y;           // 0..95
    const int bl    = lane & 15;            // A-row / b-local, B-col / d
    const int q     = lane >> 4;            // k-block = n offset within group
    const int b     = btile * 16 + bl;
    const int nbase = split * (GPS * 4);

    f32x4 acc[5];
#pragma unroll
    for (int j = 0; j < 5; ++j) acc[j] = f32x4{0.f, 0.f, 0.f, 0.f};

#pragma unroll
    for (int g = 0; g < GPS; ++g) {
        const int n = nbase + g * 4 + q;
        const f16x8 uf = *(const f16x8*)(u16 + ((size_t)b * NIN + n) * IND);
#pragma unroll
        for (int j = 0; j < 5; ++j) {
            const int o = wv * 5 + j;
            f16x8 a;
            if (MODE) {
                const _Float16 cv = cbuf[((size_t)o * NIN + n) * B + b];
#pragma unroll
                for (int i = 0; i < IND; ++i) a[i] = uf[i] * cv;
            } else {
                a = uf;
            }
            const f16x8 bf =
                *(const f16x8*)(Wt + (((size_t)n * NOUT + o) * OUTD + bl) * IND);
            acc[j] = __builtin_amdgcn_mfma_f32_16x16x32_f16(a, bf, acc[j], 0, 0, 0);
        }
    }

    const float scale = MODE ? 1.0f : 0.1f;
    _Float16* sp = spart + (size_t)split * B * M + ((size_t)btile * 16) * M;
#pragma unroll
    for (int r = 0; r < 4; ++r) {
        const int brow = q * 4 + r;
#pragma unroll
        for (int j = 0; j < 5; ++j) {
            const int o = wv * 5 + j;
            sp[(size_t)brow * M + o * OUTD + bl] = (_Float16)(acc[j][r] * scale);
        }
    }
}

// ================= k_squash: reduce NSPLIT f16 partials + squash ==================
// OUT16=1 -> write vt[o][b][d16] f16 (k_a B-fragment layout); OUT16=0 -> f32 out.
template <int OUT16>
__global__ __launch_bounds__(64) void k_squash(const _Float16* __restrict__ spart,
                                               void* __restrict__ dstv) {
    const int gid = blockIdx.x * 64 + threadIdx.x;   // 0..40959, = b*160+m
    float s = 0.f;
#pragma unroll 16
    for (int ch = 0; ch < NSPLIT; ++ch) s += (float)spart[(size_t)ch * B * M + gid];
    float ss = s * s;
    ss += __shfl_xor(ss, 1);
    ss += __shfl_xor(ss, 2);
    ss += __shfl_xor(ss, 4);
    ss += __shfl_xor(ss, 8);          // sum over the 16 d-lanes (160 % 16 == 0)
    const float v = s * sqrtf(ss) / (1.f + ss);
    if (OUT16) {
        const int b = gid / M, m = gid % M, o = m >> 4, d = m & 15;
        ((_Float16*)dstv)[((size_t)o * B + b) * 16 + d] = (_Float16)v;
    } else {
        ((float*)dstv)[gid] = v;
    }
}

// ================= k_a (MFMA v2): i in the REGISTER dim ==================
// C'[(n,i), b] = sum_d W[n,i,od]*v[b,od] via mfma 16x16x16 f16:
//   A = Wh frag (row=(n,i)=lane&15, k=d=(lane>>4)*4+j)  -> 8B contiguous
//   B = vt frag (col=b=lane&15,    k=d)                 -> vt[o][b][d16], 8B contiguous
//   C': row=(lane>>4)*4+reg = (n,i), col=lane&15 = b    [verified mapping]
// Lane reduces over i IN-REGISTER (4 fma) + ONE shfl_xor(16); owns (b, n, all o).
#define NPW  4     // n-pairs per block (one per wave)

template <int FIRST>
__global__ __launch_bounds__(256, 8) void k_a(const _Float16* __restrict__ ut,
                                              const _Float16* __restrict__ Wh,
                                              const _Float16* __restrict__ vt,
                                              _Float16* __restrict__ blog,
                                              _Float16* __restrict__ cbuf) {
    const int lane = threadIdx.x & 63;
    const int wv   = threadIdx.x >> 6;          // 0..3
    const int np   = blockIdx.x * NPW + wv;     // 0..575 n-pair
    const int col  = lane & 15;                 // b-local (B/C cols); A-row selector
    const int q    = lane >> 4;
    const int b0   = blockIdx.y * 16;
    const int b    = b0 + col;
    const int nl   = col >> 3, ii = col & 7;    // A-frag row -> (n_loc, i)
    const int nout = np * 2 + (q >> 1);         // n this lane owns post-reduction

    // u multipliers: this lane's C' rows are q*4+r -> ut[(np*16 + q*4+r)][b]
    float uf[4];
    {
        const _Float16* up = ut + ((size_t)np * 16 + q * 4) * B + b;
#pragma unroll
        for (int r = 0; r < 4; ++r) uf[r] = (float)up[(size_t)r * B];
    }

    const _Float16* wa = Wh + (((size_t)np * 2 + nl) * IND + ii) * M + q * 4;
    const f32x4 zero = {0.f, 0.f, 0.f, 0.f};

    float areg[NOUT];
#pragma unroll
    for (int o = 0; o < NOUT; ++o) {
        const f16x4 af = *(const f16x4*)(wa + o * OUTD);                       // A
        const f16x4 bfr = *(const f16x4*)(vt + ((size_t)o * B + b) * 16 + q * 4); // B
        const f32x4 cp = __builtin_amdgcn_mfma_f32_16x16x16f16(af, bfr, zero, 0, 0, 0);
        float s = cp[0] * uf[0];
        s = fmaf(cp[1], uf[1], s);
        s = fmaf(cp[2], uf[2], s);
        s = fmaf(cp[3], uf[3], s);
        s += __shfl_xor(s, 16);     // q0+q1 -> n0 full i-sum; q2+q3 -> n1
        areg[o] = s;
    }

    // b += a ; softmax over o (all lanes compute; even-q lanes write)
    float bl[NOUT];
    _Float16* bp = blog + ((size_t)nout * NOUT) * B + b;
    if (FIRST) {
#pragma unroll
        for (int o = 0; o < NOUT; ++o) {
            bl[o] = areg[o];
            if ((q & 1) == 0) bp[(size_t)o * B] = (_Float16)bl[o];
        }
    } else {
#pragma unroll
        for (int o = 0; o < NOUT; ++o) bl[o] = (float)bp[(size_t)o * B] + areg[o];
    }
    float mx = bl[0];
#pragma unroll
    for (int o = 1; o < NOUT; ++o) mx = fmaxf(mx, bl[o]);
    float sum = 0.f;
#pragma unroll
    for (int o = 0; o < NOUT; ++o) { bl[o] = __expf(bl[o] - mx); sum += bl[o]; }
    const float inv = 1.f / sum;
    if ((q & 1) == 0) {
#pragma unroll
        for (int o = 0; o < NOUT; ++o)
            cbuf[((size_t)o * NIN + nout) * B + b] = (_Float16)(bl[o] * inv);
    }
}

// ================= launch ==================
extern "C" void kernel_launch(void* const* d_in, const int* in_sizes, int n_in,
                              void* d_out, int out_size, void* d_ws, size_t ws_size,
                              hipStream_t stream) {
    const float* u = (const float*)d_in[0];   // [256,1152,8]
    const float* W = (const float*)d_in[1];   // [1152,8,160]
    float* out = (float*)d_out;               // [256,10,16] f32

    char* ws = (char*)d_ws;
    _Float16* spart = (_Float16*)(ws);                      //  7,864,320 B
    _Float16* blog  = (_Float16*)(ws + 7864320);            //  5,898,240 B
    _Float16* cbuf  = (_Float16*)(ws + 13762560);           //  5,898,240 B
    _Float16* vt    = (_Float16*)(ws + 19660800);           //     81,920 B
    _Float16* Wh    = (_Float16*)(ws + 19742720);           //  2,949,120 B
    _Float16* Wt    = (_Float16*)(ws + 22691840);           //  2,949,120 B
    _Float16* u16   = (_Float16*)(ws + 25640960);           //  4,718,592 B
    _Float16* ut    = (_Float16*)(ws + 30359552);           //  4,718,592 B
    // total ~35.1 MB

    const dim3 gs(16, NSPLIT);                      // (16, 96)
    const dim3 ga(NIN / 2 / NPW, B / 16);           // (144, 16)

    // one-time preps
    k_w16<<<1440, 256, 0, stream>>>(W, Wh);
    k_wt<<<NIN, 256, 0, stream>>>(W, Wt);
    k_u16<<<2304, 256, 0, stream>>>(u, u16);
    k_ut<<<dim3(K / 64, B / 64), 256, 0, stream>>>(u, ut);

    // iter 0: uniform c = 0.1
    k_su<0><<<gs, 128, 0, stream>>>(u16, Wt, cbuf, spart);
    k_squash<1><<<640, 64, 0, stream>>>(spart, vt);
    // a0 -> blog=b1, c1
    k_a<1><<<ga, 256, 0, stream>>>(ut, Wh, vt, blog, cbuf);
    // s1 -> v1
    k_su<1><<<gs, 128, 0, stream>>>(u16, Wt, cbuf, spart);
    k_squash<1><<<640, 64, 0, stream>>>(spart, vt);
    // a1 -> b2 (in-register), c2
    k_a<0><<<ga, 256, 0, stream>>>(ut, Wh, vt, blog, cbuf);
    // s2 -> v2 = output
    k_su<1><<<gs, 128, 0, stream>>>(u16, Wt, cbuf, spart);
    k_squash<0><<<640, 64, 0, stream>>>(spart, out);
}

// Round 14
// 77.535 us; speedup vs baseline: 2.0296x; 1.1578x over previous
//
#include <hip/hip_runtime.h>
#include <math.h>

#define B    256
#define NIN  1152
#define IND  8
#define NOUT 10
#define OUTD 16
#define M    160          // NOUT*OUTD
#define K    9216         // NIN*IND

typedef _Float16 h2    __attribute__((ext_vector_type(2)));
typedef _Float16 f16x4 __attribute__((ext_vector_type(4)));
typedef _Float16 f16x8 __attribute__((ext_vector_type(8)));
typedef float    f32x4 __attribute__((ext_vector_type(4)));
struct __align__(16) H8 { h2 h[4]; };   // 8 f16
struct __align__(8)  H4 { h2 h[2]; };   // 4 f16

// ================= prep: W -> Wh (f16 same layout) + Wt [n][o][d][i] =================
__global__ __launch_bounds__(256) void k_prep_w(const float* __restrict__ W,
                                                _Float16* __restrict__ Wh,
                                                _Float16* __restrict__ Wt) {
    __shared__ float wl[IND * M];   // 5120 B
    const int n = blockIdx.x;
    const float* src = W + (size_t)n * IND * M;
    for (int t = threadIdx.x; t < IND * M / 4; t += 256)
        *(float4*)(wl + t * 4) = *(const float4*)(src + (size_t)t * 4);
    __syncthreads();
    // Wh: 640 h2 chunks
    _Float16* wh = Wh + (size_t)n * IND * M;
    for (int t = threadIdx.x; t < IND * M / 2; t += 256) {
        h2 p = {(_Float16)wl[2 * t], (_Float16)wl[2 * t + 1]};
        *(h2*)(wh + 2 * t) = p;
    }
    // Wt: [o][d][i]
    if (threadIdx.x < 160) {
        const int o = threadIdx.x >> 4, d = threadIdx.x & 15;
        f16x8 outv;
#pragma unroll
        for (int i = 0; i < IND; ++i) outv[i] = (_Float16)wl[i * M + o * OUTD + d];
        *(f16x8*)(Wt + (((size_t)n * NOUT + o) * OUTD + d) * IND) = outv;
    }
}

// ================= prep: u -> u16 (f16 same layout) + ut [k][b] transpose =================
__global__ __launch_bounds__(256) void k_prep_u(const float* __restrict__ u,
                                                _Float16* __restrict__ u16,
                                                _Float16* __restrict__ ut) {
    __shared__ _Float16 lt[64][80];   // pad 80 -> 160B row stride
    const int k0 = blockIdx.x * 64;   // 144
    const int b0 = blockIdx.y * 64;   // 4
#pragma unroll
    for (int p = 0; p < 4; ++p) {
        const int r = (threadIdx.x >> 4) + p * 16;   // b-local 0..63
        const int c = (threadIdx.x & 15) * 4;        // k-local
        const float4 f = *(const float4*)(u + (size_t)(b0 + r) * K + k0 + c);
        H4 pk;
        pk.h[0] = h2{(_Float16)f.x, (_Float16)f.y};
        pk.h[1] = h2{(_Float16)f.z, (_Float16)f.w};
        *(H4*)(u16 + (size_t)(b0 + r) * K + k0 + c) = pk;   // coalesced 8B
        lt[c + 0][r] = (_Float16)f.x;
        lt[c + 1][r] = (_Float16)f.y;
        lt[c + 2][r] = (_Float16)f.z;
        lt[c + 3][r] = (_Float16)f.w;
    }
    __syncthreads();
#pragma unroll
    for (int p = 0; p < 2; ++p) {
        const int kr = (threadIdx.x >> 3) + p * 32;  // k-local 0..63
        const int bc = (threadIdx.x & 7) * 8;        // b-local
        *(uint4*)(ut + (size_t)(k0 + kr) * B + b0 + bc) = *(const uint4*)&lt[kr][bc];
    }
}

// ================= k_su: MFMA 16x16x32 f16, 4-wave blocks, LDS pair-reduce ==========
// grid (16 btiles, 48 splits), 256 thr = 4 waves: wp = w&1 (o-half), gh = w>>1 (g-half).
// Each wave: 3 n-groups x 5 o MFMAs (verified round-11 fragment mapping).
// gh=1 waves dump acc to LDS; gh=0 waves add + write spart (halves spart traffic).
#define NSPLIT 48
#define GPS    6      // n-groups (of 4 n) per split: 48*6*4 = 1152

template <int MODE>   // 0: c = 0.1 uniform; 1: read cbuf (f16)
__global__ __launch_bounds__(256, 8) void k_su(const _Float16* __restrict__ u16,
                                               const _Float16* __restrict__ Wt,
                                               const _Float16* __restrict__ cbuf,
                                               _Float16* __restrict__ spart) {
    __shared__ f32x4 red[2][5][64];         // 10240 B
    const int lane  = threadIdx.x & 63;
    const int w     = threadIdx.x >> 6;     // 0..3
    const int wp    = w & 1;                // o-half
    const int gh    = w >> 1;               // g-half
    const int btile = blockIdx.x;           // 0..15
    const int split = blockIdx.y;           // 0..47
    const int bl    = lane & 15;            // A-row / b-local, B-col / d
    const int q     = lane >> 4;            // k-block = n offset within group
    const int b     = btile * 16 + bl;
    const int nbase = split * (GPS * 4);

    f32x4 acc[5];
#pragma unroll
    for (int j = 0; j < 5; ++j) acc[j] = f32x4{0.f, 0.f, 0.f, 0.f};

#pragma unroll
    for (int gg = 0; gg < 3; ++gg) {
        const int g = gh * 3 + gg;
        const int n = nbase + g * 4 + q;
        const f16x8 uf = *(const f16x8*)(u16 + ((size_t)b * NIN + n) * IND);
#pragma unroll
        for (int j = 0; j < 5; ++j) {
            const int o = wp * 5 + j;
            f16x8 a;
            if (MODE) {
                const _Float16 cv = cbuf[((size_t)o * NIN + n) * B + b];
#pragma unroll
                for (int i = 0; i < IND; ++i) a[i] = uf[i] * cv;
            } else {
                a = uf;
            }
            const f16x8 bf =
                *(const f16x8*)(Wt + (((size_t)n * NOUT + o) * OUTD + bl) * IND);
            acc[j] = __builtin_amdgcn_mfma_f32_16x16x32_f16(a, bf, acc[j], 0, 0, 0);
        }
    }

    if (gh == 1) {
#pragma unroll
        for (int j = 0; j < 5; ++j) red[wp][j][lane] = acc[j];
    }
    __syncthreads();
    if (gh == 0) {
        const float scale = MODE ? 1.0f : 0.1f;
        _Float16* sp = spart + (size_t)split * B * M + ((size_t)btile * 16) * M;
#pragma unroll
        for (int j = 0; j < 5; ++j) {
            const f32x4 other = red[wp][j][lane];
            const int o = wp * 5 + j;
#pragma unroll
            for (int r = 0; r < 4; ++r) {
                const int brow = q * 4 + r;
                sp[(size_t)brow * M + o * OUTD + bl] =
                    (_Float16)((acc[j][r] + other[r]) * scale);
            }
        }
    }
}

// ================= k_squash: reduce NSPLIT f16 partials + squash ==================
// grid 160 x 256. OUT16=1 -> vt[o][b][d16] f16 (k_a B-frag layout); OUT16=0 -> f32.
template <int OUT16>
__global__ __launch_bounds__(256) void k_squash(const _Float16* __restrict__ spart,
                                                void* __restrict__ dstv) {
    const int gid = blockIdx.x * 256 + threadIdx.x;   // 0..40959, = b*160+m
    float s = 0.f;
#pragma unroll 16
    for (int ch = 0; ch < NSPLIT; ++ch) s += (float)spart[(size_t)ch * B * M + gid];
    float ss = s * s;
    ss += __shfl_xor(ss, 1);
    ss += __shfl_xor(ss, 2);
    ss += __shfl_xor(ss, 4);
    ss += __shfl_xor(ss, 8);          // sum over the 16 d-lanes (16 | 64, aligned)
    const float v = s * sqrtf(ss) / (1.f + ss);
    if (OUT16) {
        const int b = gid / M, m = gid % M, o = m >> 4, d = m & 15;
        ((_Float16*)dstv)[((size_t)o * B + b) * 16 + d] = (_Float16)v;
    } else {
        ((float*)dstv)[gid] = v;
    }
}

// ================= k_a (MFMA v2, round-13 verified): i in the REGISTER dim ==========
#define NPW  4     // n-pairs per block (one per wave)

template <int FIRST>
__global__ __launch_bounds__(256, 8) void k_a(const _Float16* __restrict__ ut,
                                              const _Float16* __restrict__ Wh,
                                              const _Float16* __restrict__ vt,
                                              _Float16* __restrict__ blog,
                                              _Float16* __restrict__ cbuf) {
    const int lane = threadIdx.x & 63;
    const int wv   = threadIdx.x >> 6;          // 0..3
    const int np   = blockIdx.x * NPW + wv;     // 0..575 n-pair
    const int col  = lane & 15;                 // b-local (B/C cols); A-row selector
    const int q    = lane >> 4;
    const int b0   = blockIdx.y * 16;
    const int b    = b0 + col;
    const int nl   = col >> 3, ii = col & 7;    // A-frag row -> (n_loc, i)
    const int nout = np * 2 + (q >> 1);         // n this lane owns post-reduction

    float uf[4];
    {
        const _Float16* up = ut + ((size_t)np * 16 + q * 4) * B + b;
#pragma unroll
        for (int r = 0; r < 4; ++r) uf[r] = (float)up[(size_t)r * B];
    }

    const _Float16* wa = Wh + (((size_t)np * 2 + nl) * IND + ii) * M + q * 4;
    const f32x4 zero = {0.f, 0.f, 0.f, 0.f};

    float areg[NOUT];
#pragma unroll
    for (int o = 0; o < NOUT; ++o) {
        const f16x4 af = *(const f16x4*)(wa + o * OUTD);                          // A
        const f16x4 bfr = *(const f16x4*)(vt + ((size_t)o * B + b) * 16 + q * 4); // B
        const f32x4 cp = __builtin_amdgcn_mfma_f32_16x16x16f16(af, bfr, zero, 0, 0, 0);
        float s = cp[0] * uf[0];
        s = fmaf(cp[1], uf[1], s);
        s = fmaf(cp[2], uf[2], s);
        s = fmaf(cp[3], uf[3], s);
        s += __shfl_xor(s, 16);     // q0+q1 -> n0 full i-sum; q2+q3 -> n1
        areg[o] = s;
    }

    float bl[NOUT];
    _Float16* bp = blog + ((size_t)nout * NOUT) * B + b;
    if (FIRST) {
#pragma unroll
        for (int o = 0; o < NOUT; ++o) {
            bl[o] = areg[o];
            if ((q & 1) == 0) bp[(size_t)o * B] = (_Float16)bl[o];
        }
    } else {
#pragma unroll
        for (int o = 0; o < NOUT; ++o) bl[o] = (float)bp[(size_t)o * B] + areg[o];
    }
    float mx = bl[0];
#pragma unroll
    for (int o = 1; o < NOUT; ++o) mx = fmaxf(mx, bl[o]);
    float sum = 0.f;
#pragma unroll
    for (int o = 0; o < NOUT; ++o) { bl[o] = __expf(bl[o] - mx); sum += bl[o]; }
    const float inv = 1.f / sum;
    if ((q & 1) == 0) {
#pragma unroll
        for (int o = 0; o < NOUT; ++o)
            cbuf[((size_t)o * NIN + nout) * B + b] = (_Float16)(bl[o] * inv);
    }
}

// ================= launch ==================
extern "C" void kernel_launch(void* const* d_in, const int* in_sizes, int n_in,
                              void* d_out, int out_size, void* d_ws, size_t ws_size,
                              hipStream_t stream) {
    const float* u = (const float*)d_in[0];   // [256,1152,8]
    const float* W = (const float*)d_in[1];   // [1152,8,160]
    float* out = (float*)d_out;               // [256,10,16] f32

    char* ws = (char*)d_ws;
    _Float16* spart = (_Float16*)(ws);                      //  3,932,160 B
    _Float16* blog  = (_Float16*)(ws + 3932160);            //  5,898,240 B
    _Float16* cbuf  = (_Float16*)(ws + 9830400);            //  5,898,240 B
    _Float16* vt    = (_Float16*)(ws + 15728640);           //     81,920 B
    _Float16* Wh    = (_Float16*)(ws + 15810560);           //  2,949,120 B
    _Float16* Wt    = (_Float16*)(ws + 18759680);           //  2,949,120 B
    _Float16* ut    = (_Float16*)(ws + 21708800);           //  4,718,592 B
    _Float16* u16   = (_Float16*)(ws + 26427392);           //  4,718,592 B
    // total 31,145,984 B (~31.1 MB)

    const dim3 gs(16, NSPLIT);                      // (16, 48) = 768 blocks
    const dim3 ga(NIN / 2 / NPW, B / 16);           // (144, 16)

    // fused one-time preps
    k_prep_w<<<NIN, 256, 0, stream>>>(W, Wh, Wt);
    k_prep_u<<<dim3(K / 64, B / 64), 256, 0, stream>>>(u, u16, ut);

    // iter 0: uniform c = 0.1
    k_su<0><<<gs, 256, 0, stream>>>(u16, Wt, cbuf, spart);
    k_squash<1><<<160, 256, 0, stream>>>(spart, vt);
    // a0 -> blog=b1, c1
    k_a<1><<<ga, 256, 0, stream>>>(ut, Wh, vt, blog, cbuf);
    // s1 -> v1
    k_su<1><<<gs, 256, 0, stream>>>(u16, Wt, cbuf, spart);
    k_squash<1><<<160, 256, 0, stream>>>(spart, vt);
    // a1 -> b2 (in-register), c2
    k_a<0><<<ga, 256, 0, stream>>>(ut, Wh, vt, blog, cbuf);
    // s2 -> v2 = output
    k_su<1><<<gs, 256, 0, stream>>>(u16, Wt, cbuf, spart);
    k_squash<0><<<160, 256, 0, stream>>>(spart, out);
}